// Round 8
// baseline (480.801 us; speedup 1.0000x reference)
//
#include <hip/hip_runtime.h>

#define HH 20
#define WW 20
#define TT 96
#define BB 64
#define SIG 306
#define NFC 17
#define TSTRIDE 260    // feat per-t stride: 16pix*16ch + 4  (== 4 mod 32: conflict-free b128 writes)
#define CHUNK 16
#define NCHUNK 6
#define XT 199         // xs per-t stride
#define NTILE 25
#define REDA 4608      // epilogue reduction arena: 256*17 + 256 floats (overlaid on feat)

typedef float float4u __attribute__((ext_vector_type(4), aligned(4)));

// ---------------------------------------------------------------------------
// Kernel 1 (R14): conv + signature + FUSED MLP-1 -> 25x64x32 partials.
// Main loop = frozen R2 structure. Epilogue = R7's verified fused MLP-1
// (in-register sig x w1 rows -> h[32], block tree-reduce, one 128B partial).
// SINGLE CHANGE vs R7: block mapping reverted to R2's b-major
// (b=blk/25, tile=blk%25). R7's tile-major XCD chunking put same-b adjacent
// tiles (halo sharers) on the SAME XCD -> R3's dedup-serialization pathology
// (main loop ~205 us @ 585 GB/s). b-major puts halo sharers on different
// XCDs (replicated fetch, 8-L2 parallelism — proven R2/R3/R4) and spreads
// same-tile blocks (25 apart) across all XCDs; w1 reuse among ~700 resident
// blocks still dedups (R7 FETCH showed only +39 MB for w1).
// ---------------------------------------------------------------------------
template<bool ATOMIC>
__global__ __launch_bounds__(256) void sig_mlp1(
    const float* __restrict__ x,    // (64,96,4,20,20)
    const float* __restrict__ cw,   // (12,4,3,3)
    const float* __restrict__ w1,   // (122400,32)
    float* __restrict__ part)       // (25,64,32) or (64,32) atomic
{
  __shared__ __align__(16) float feat[REDA];   // main: 15*260+... (4164) / epi: red arena
  __shared__ __align__(16) float xs[CHUNK * XT];

  const int tid = threadIdx.x;
  const int blk = blockIdx.x;
  const int b = blk / 25;          // b-major: consecutive blocks = same b,
  const int tile = blk % 25;       // adjacent tiles -> different XCDs
  const int th4 = (tile / 5) * 4, tw4 = (tile % 5) * 4;
  const float* xb0 = x + (size_t)b * TT * 1600;

  // ---- staging precompute: 2304 = 9*256 halo values per chunk ----
  int g_off[9], l_off[9];
  #pragma unroll
  for (int r = 0; r < 9; r++) {
    int idx = r * 256 + tid;
    int t = idx / 144, q = idx % 144;
    int ci = q / 36, pos = q % 36, row = pos / 6, col = pos % 6;
    int gr = th4 - 1 + row, gc = tw4 - 1 + col;
    bool valid = (gr >= 0 && gr < HH && gc >= 0 && gc < WW);
    g_off[r] = valid ? (t * 1600 + ci * 400 + gr * WW + gc) : -1;
    l_off[r] = t * XT + ci * 48 + row * 8 + col;
  }

  const int cpix = tid >> 4, ctt = tid & 15;
  const int cpy = cpix >> 2, cpx = cpix & 3;

  const int p2 = tid >> 4;
  const int rr = tid & 15, it = rr >> 2, jt = rr & 3;
  const int i0 = it * 4, j0 = jt * 4;

  float accv[4][4];
  float f0a[4], f0b[4], pa[4], pb[4], fsum[4];
  float rg[9];                       // prefetch registers (live across p2)
  #pragma unroll
  for (int i = 0; i < 4; i++) {
    #pragma unroll
    for (int j = 0; j < 4; j++) accv[i][j] = 0.f;
  }

  auto loadrg = [&](int chunk) {
    const float* xbc = xb0 + (size_t)chunk * CHUNK * 1600;
    #pragma unroll
    for (int r = 0; r < 9; r++)
      rg[r] = (g_off[r] >= 0) ? xbc[g_off[r]] : 0.f;
  };
  auto writexs = [&]() {
    #pragma unroll
    for (int r = 0; r < 9; r++) xs[l_off[r]] = rg[r];
  };

  auto conv = [&]() {
    float win[4][9];
    const int wb2 = ctt * XT;
    #pragma unroll
    for (int ci = 0; ci < 4; ci++)
      #pragma unroll
      for (int dy = 0; dy < 3; dy++)
        #pragma unroll
        for (int dxx = 0; dxx < 3; dxx++)
          win[ci][dy * 3 + dxx] = xs[wb2 + ci * 48 + (cpy + dy) * 8 + (cpx + dxx)];

    float fk[12];
    #pragma unroll
    for (int k = 0; k < 12; k++) {
      float a = 0.f;
      #pragma unroll
      for (int ci = 0; ci < 4; ci++) {
        #pragma unroll
        for (int p = 0; p < 9; p++)
          a += win[ci][p] * cw[k * 36 + ci * 9 + p];   // uniform -> scalar load
      }
      fk[k] = a;
    }
    float* fr = &feat[ctt * TSTRIDE + cpix * 16];
    *reinterpret_cast<float4*>(fr + 0)  = make_float4(fk[0], fk[1], fk[2], fk[3]);
    *reinterpret_cast<float4*>(fr + 4)  = make_float4(fk[4], fk[5], fk[6], fk[7]);
    *reinterpret_cast<float4*>(fr + 8)  = make_float4(fk[8], fk[9], fk[10], fk[11]);
    *reinterpret_cast<float4*>(fr + 12) = make_float4(win[0][4], win[1][4], win[2][4], win[3][4]);
  };

  auto p2step = [&](int tt) {
    const float* row = &feat[tt * TSTRIDE + p2 * 16];
    const float4 a4 = *reinterpret_cast<const float4*>(row + i0);
    const float4 b4 = *reinterpret_cast<const float4*>(row + j0);
    float fa[4] = {a4.x, a4.y, a4.z, a4.w};
    float fb[4] = {b4.x, b4.y, b4.z, b4.w};
    float sa[4], db[4];
    #pragma unroll
    for (int i = 0; i < 4; i++) { sa[i] = fa[i] + pa[i]; db[i] = fb[i] - pb[i]; }
    #pragma unroll
    for (int i = 0; i < 4; i++)
      #pragma unroll
      for (int j = 0; j < 4; j++) accv[i][j] += sa[i] * db[j];
    #pragma unroll
    for (int i = 0; i < 4; i++) { fsum[i] += fa[i]; pa[i] = fa[i]; pb[i] = fb[i]; }
  };

  // ===== chunk 0 (peeled) =====
  loadrg(0);
  writexs();
  __syncthreads();                 // syncB: xs ready
  conv();
  loadrg(1);                       // prefetch chunk 1 (latency hides under p2)
  __syncthreads();                 // syncC: feat ready
  {
    const float* r0 = &feat[p2 * 16];
    const float4 a4 = *reinterpret_cast<const float4*>(r0 + i0);
    const float4 b4 = *reinterpret_cast<const float4*>(r0 + j0);
    f0a[0] = a4.x; f0a[1] = a4.y; f0a[2] = a4.z; f0a[3] = a4.w;
    f0b[0] = b4.x; f0b[1] = b4.y; f0b[2] = b4.z; f0b[3] = b4.w;
    #pragma unroll
    for (int i = 0; i < 4; i++) { pa[i] = f0a[i]; pb[i] = f0b[i]; fsum[i] = f0a[i]; }
  }
  #pragma unroll
  for (int tt = 1; tt < CHUNK; tt++) p2step(tt);

  // ===== chunks 1..5 =====
  for (int chunk = 1; chunk < NCHUNK; chunk++) {
    writexs();                     // write prefetched regs (xs reuse safe: syncC)
    __syncthreads();               // syncB: xs ready + feat(prev p2) protected
    conv();
    if (chunk < NCHUNK - 1) loadrg(chunk + 1);
    __syncthreads();               // syncC: feat ready + xs-read complete
    #pragma unroll
    for (int tt = 0; tt < CHUNK; tt++) p2step(tt);
  }

  // ===== fused MLP-1 epilogue (byte-identical to R7, verified) =====
  {
    const int ph = th4 + (p2 >> 2), pw = tw4 + (p2 & 3);
    const int pixbase = (ph * WW + pw) * SIG;      // w1 row base for this pixel
    float lv1b[4];
    #pragma unroll
    for (int j = 0; j < 4; j++) lv1b[j] = pb[j] - f0b[j];

    // special rows, balanced across jt (f0a/pa/fsum shared per-it):
    float spv[4]; int spr[4]; int nsp = 0;
    if (jt == 0) {                                 // lvl1, channels i0..i0+3
      nsp = 4;
      #pragma unroll
      for (int ii = 0; ii < 4; ii++) { spv[ii] = pa[ii] - f0a[ii]; spr[ii] = pixbase + i0 + ii; }
    } else if (jt == 1) {                          // lvl2[c][16] (A x t)
      nsp = 4;
      #pragma unroll
      for (int ii = 0; ii < 4; ii++) {
        spv[ii] = (fsum[ii] - 95.5f * f0a[ii] - 0.5f * pa[ii]) * (1.f / 95.f);
        spr[ii] = pixbase + NFC + (i0 + ii) * NFC + 16;
      }
    } else if (jt == 2) {                          // lvl2[16][c] (t x B)
      nsp = 4;
      #pragma unroll
      for (int ii = 0; ii < 4; ii++) {
        spv[ii] = (95.5f * pa[ii] + 0.5f * f0a[ii] - fsum[ii]) * (1.f / 95.f);
        spr[ii] = pixbase + NFC + 16 * NFC + (i0 + ii);
      }
    } else {                                       // jt == 3: const rows
      if (it == 0) { nsp = 1; spv[0] = 1.0f; spr[0] = pixbase + 16; }
      if (it == 1) { nsp = 1; spv[0] = 0.5f; spr[0] = pixbase + NFC + 16 * NFC + 16; }
    }

    float hs0 = 0.f, hs1 = 0.f;
    #pragma unroll
    for (int half = 0; half < 2; half++) {
      const int n0 = half * 16;
      float h[16];
      #pragma unroll
      for (int q = 0; q < 16; q++) h[q] = 0.f;

      #pragma unroll
      for (int ii = 0; ii < 4; ii++) {
        #pragma unroll
        for (int jj = 0; jj < 4; jj++) {
          const float val = 0.5f * accv[ii][jj] - f0a[ii] * lv1b[jj];
          const float* wr = w1 + (size_t)(pixbase + NFC + (i0 + ii) * NFC + (j0 + jj)) * 32 + n0;
          const float4 wa = *reinterpret_cast<const float4*>(wr);
          const float4 wb = *reinterpret_cast<const float4*>(wr + 4);
          const float4 wc = *reinterpret_cast<const float4*>(wr + 8);
          const float4 wd = *reinterpret_cast<const float4*>(wr + 12);
          h[0]  += val * wa.x; h[1]  += val * wa.y; h[2]  += val * wa.z; h[3]  += val * wa.w;
          h[4]  += val * wb.x; h[5]  += val * wb.y; h[6]  += val * wb.z; h[7]  += val * wb.w;
          h[8]  += val * wc.x; h[9]  += val * wc.y; h[10] += val * wc.z; h[11] += val * wc.w;
          h[12] += val * wd.x; h[13] += val * wd.y; h[14] += val * wd.z; h[15] += val * wd.w;
        }
      }
      #pragma unroll
      for (int sp = 0; sp < 4; sp++) {             // static unroll (rule #20)
        if (sp < nsp) {
          const float val = spv[sp];
          const float* wr = w1 + (size_t)spr[sp] * 32 + n0;
          const float4 wa = *reinterpret_cast<const float4*>(wr);
          const float4 wb = *reinterpret_cast<const float4*>(wr + 4);
          const float4 wc = *reinterpret_cast<const float4*>(wr + 8);
          const float4 wd = *reinterpret_cast<const float4*>(wr + 12);
          h[0]  += val * wa.x; h[1]  += val * wa.y; h[2]  += val * wa.z; h[3]  += val * wa.w;
          h[4]  += val * wb.x; h[5]  += val * wb.y; h[6]  += val * wb.z; h[7]  += val * wb.w;
          h[8]  += val * wc.x; h[9]  += val * wc.y; h[10] += val * wc.z; h[11] += val * wc.w;
          h[12] += val * wd.x; h[13] += val * wd.y; h[14] += val * wd.z; h[15] += val * wd.w;
        }
      }

      // ---- block-reduce h[16] over 256 threads (deterministic tree) ----
      __syncthreads();             // feat reads (p2 / prev half) complete
      #pragma unroll
      for (int q = 0; q < 16; q++) feat[tid * 17 + q] = h[q];   // stride-17: no conflicts
      __syncthreads();
      {
        const int r0 = tid >> 4, nn = tid & 15;
        float s = 0.f;
        #pragma unroll
        for (int j2 = 0; j2 < 16; j2++) s += feat[(r0 + 16 * j2) * 17 + nn];
        feat[256 * 17 + tid] = s;
      }
      __syncthreads();
      if (tid < 16) {
        float s = 0.f;
        #pragma unroll
        for (int r = 0; r < 16; r++) s += feat[256 * 17 + r * 16 + tid];
        if (half == 0) hs0 = s; else hs1 = s;
      }
    }

    if (tid < 16) {
      if (ATOMIC) {
        atomicAdd(&part[b * 32 + tid], hs0);
        atomicAdd(&part[b * 32 + 16 + tid], hs1);
      } else {
        part[tile * (BB * 32) + b * 32 + tid] = hs0;
        part[tile * (BB * 32) + b * 32 + 16 + tid] = hs1;
      }
    }
  }
}

// ---------------------------------------------------------------------------
// Kernel 2: partial-reduce + MLP layers 2-4. 64 blocks (one per b) x 256 thr.
// npart = 25 (tile partials), fixed order -> deterministic.
// ---------------------------------------------------------------------------
__global__ __launch_bounds__(256) void mlp_tail(
    const float* __restrict__ part, int npart, const float* __restrict__ b1,
    const float* __restrict__ w2, const float* __restrict__ b2,
    const float* __restrict__ w3, const float* __restrict__ b3,
    const float* __restrict__ w4, const float* __restrict__ b4,
    float* __restrict__ out)
{
  __shared__ float red[8][33];
  const int tid = threadIdx.x;
  const int n = tid & 31;
  const int s = tid >> 5;            // 0..7
  const int b = blockIdx.x;

  float sum = 0.f;
  for (int p = s; p < npart; p += 8)
    sum += part[(size_t)p * (BB * 32) + b * 32 + n];
  red[s][n] = sum;
  __syncthreads();

  if (tid < 32) {
    float acc = red[0][n];
    #pragma unroll
    for (int q = 1; q < 8; q++) acc += red[q][n];

    float h = fmaxf(acc + b1[n], 0.f);

    float v = b2[n];
    #pragma unroll
    for (int k = 0; k < 32; k++)
      v += __shfl(h, k, 64) * w2[k * 32 + n];
    h = fmaxf(v, 0.f);

    v = b3[n];
    #pragma unroll
    for (int k = 0; k < 32; k++)
      v += __shfl(h, k, 64) * w3[k * 32 + n];
    h = fmaxf(v, 0.f);

    float p = h * w4[n];
    #pragma unroll
    for (int o = 16; o >= 1; o >>= 1) p += __shfl_xor(p, o, 64);
    if (n == 0) out[b] = p + b4[0];
  }
}

extern "C" void kernel_launch(void* const* d_in, const int* in_sizes, int n_in,
                              void* d_out, int out_size, void* d_ws, size_t ws_size,
                              hipStream_t stream) {
  const float* x  = (const float*)d_in[0];
  const float* cw = (const float*)d_in[1];
  const float* w1 = (const float*)d_in[3];
  const float* b1 = (const float*)d_in[4];
  const float* w2 = (const float*)d_in[5];
  const float* b2 = (const float*)d_in[6];
  const float* w3 = (const float*)d_in[7];
  const float* b3 = (const float*)d_in[8];
  const float* w4 = (const float*)d_in[9];
  const float* b4 = (const float*)d_in[10];
  float* out = (float*)d_out;

  const size_t part_bytes = (size_t)NTILE * BB * 32 * sizeof(float);  // 204.8 KB

  if (ws_size >= part_bytes) {
    float* part = (float*)d_ws;
    sig_mlp1<false><<<dim3(1600), dim3(256), 0, stream>>>(x, cw, w1, part);
    mlp_tail<<<dim3(64), dim3(256), 0, stream>>>(part, NTILE, b1, w2, b2, w3, b3, w4, b4, out);
  } else {
    float* acc = (float*)d_ws;   // 8 KB
    hipMemsetAsync(acc, 0, BB * 32 * sizeof(float), stream);
    sig_mlp1<true><<<dim3(1600), dim3(256), 0, stream>>>(x, cw, w1, acc);
    mlp_tail<<<dim3(64), dim3(256), 0, stream>>>(acc, 1, b1, w2, b2, w3, b3, w4, b4, out);
  }
}

// Round 9
// 391.567 us; speedup vs baseline: 1.2279x; 1.2279x over previous
//
#include <hip/hip_runtime.h>

#define HH 20
#define WW 20
#define TT 96
#define BB 64
#define SIG 306
#define NFC 17
#define TSTRIDE 260    // feat per-t stride: 16pix*16ch + 4  (== 4 mod 32: conflict-free b128 writes)
#define CHUNK 16
#define NCHUNK 6
#define XT 199         // xs per-t stride
#define NTILE 25
#define REDA 4608      // epilogue reduction arena: 256*17 + 256 floats (overlaid on feat)

typedef float float4u __attribute__((ext_vector_type(4), aligned(4)));

// ---------------------------------------------------------------------------
// Kernel 1 (R15): conv + signature + FUSED MLP-1 -> 25x64x32 partials.
// Main loop = frozen R2 structure; epilogue = verified fused MLP-1.
// BLOCK MAP (the whole round): dual-locality XCD mapping.
//   x wants: same-b adjacent tiles on DIFFERENT XCDs (replicated halo fetch,
//     8-L2 parallelism — R3/R8 proved forcing dedup serializes).
//   w1 wants: same-tile blocks on the SAME XCD, temporally adjacent (626 KB
//     slice L2-fits — R7 proved dedup works; R8's b-major got 1.35 GB FETCH
//     = zero w1 reuse, pure BW-bound 397 us).
// With XCD = blockIdx%8 (confirmed R3):
//   blk<1536: r=blk&7, q=blk>>3; tile=r+8*(q>>6) (tiles r,r+8,r+16), b=q&63
//     -> same tile = one XCD, 64 blocks spaced 8 apart (co-resident; w1 L2-hit)
//     -> same b = 8 consecutive blocks, tiles 8k..8k+7, all 8 XCDs (R2 x-pattern)
//   blk>=1536: tile=24, b=blk-1536 (w1 replicated x8 = +5 MB, trailing).
// ---------------------------------------------------------------------------
template<bool ATOMIC>
__global__ __launch_bounds__(256) void sig_mlp1(
    const float* __restrict__ x,    // (64,96,4,20,20)
    const float* __restrict__ cw,   // (12,4,3,3)
    const float* __restrict__ w1,   // (122400,32)
    float* __restrict__ part)       // (25,64,32) or (64,32) atomic
{
  __shared__ __align__(16) float feat[REDA];   // main: 15*260+... (4164) / epi: red arena
  __shared__ __align__(16) float xs[CHUNK * XT];

  const int tid = threadIdx.x;
  const int blk = blockIdx.x;
  int tile, b;
  if (blk < 1536) {
    const int r = blk & 7, q = blk >> 3;       // q in [0,192)
    tile = r + 8 * (q >> 6);                   // r, r+8, r+16
    b = q & 63;
  } else {
    tile = 24;
    b = blk - 1536;
  }
  const int th4 = (tile / 5) * 4, tw4 = (tile % 5) * 4;
  const float* xb0 = x + (size_t)b * TT * 1600;

  // ---- staging precompute: 2304 = 9*256 halo values per chunk ----
  int g_off[9], l_off[9];
  #pragma unroll
  for (int r = 0; r < 9; r++) {
    int idx = r * 256 + tid;
    int t = idx / 144, q = idx % 144;
    int ci = q / 36, pos = q % 36, row = pos / 6, col = pos % 6;
    int gr = th4 - 1 + row, gc = tw4 - 1 + col;
    bool valid = (gr >= 0 && gr < HH && gc >= 0 && gc < WW);
    g_off[r] = valid ? (t * 1600 + ci * 400 + gr * WW + gc) : -1;
    l_off[r] = t * XT + ci * 48 + row * 8 + col;
  }

  const int cpix = tid >> 4, ctt = tid & 15;
  const int cpy = cpix >> 2, cpx = cpix & 3;

  const int p2 = tid >> 4;
  const int rr = tid & 15, it = rr >> 2, jt = rr & 3;
  const int i0 = it * 4, j0 = jt * 4;

  float accv[4][4];
  float f0a[4], f0b[4], pa[4], pb[4], fsum[4];
  float rg[9];                       // prefetch registers (live across p2)
  #pragma unroll
  for (int i = 0; i < 4; i++) {
    #pragma unroll
    for (int j = 0; j < 4; j++) accv[i][j] = 0.f;
  }

  auto loadrg = [&](int chunk) {
    const float* xbc = xb0 + (size_t)chunk * CHUNK * 1600;
    #pragma unroll
    for (int r = 0; r < 9; r++)
      rg[r] = (g_off[r] >= 0) ? xbc[g_off[r]] : 0.f;
  };
  auto writexs = [&]() {
    #pragma unroll
    for (int r = 0; r < 9; r++) xs[l_off[r]] = rg[r];
  };

  auto conv = [&]() {
    float win[4][9];
    const int wb2 = ctt * XT;
    #pragma unroll
    for (int ci = 0; ci < 4; ci++)
      #pragma unroll
      for (int dy = 0; dy < 3; dy++)
        #pragma unroll
        for (int dxx = 0; dxx < 3; dxx++)
          win[ci][dy * 3 + dxx] = xs[wb2 + ci * 48 + (cpy + dy) * 8 + (cpx + dxx)];

    float fk[12];
    #pragma unroll
    for (int k = 0; k < 12; k++) {
      float a = 0.f;
      #pragma unroll
      for (int ci = 0; ci < 4; ci++) {
        #pragma unroll
        for (int p = 0; p < 9; p++)
          a += win[ci][p] * cw[k * 36 + ci * 9 + p];   // uniform -> scalar load
      }
      fk[k] = a;
    }
    float* fr = &feat[ctt * TSTRIDE + cpix * 16];
    *reinterpret_cast<float4*>(fr + 0)  = make_float4(fk[0], fk[1], fk[2], fk[3]);
    *reinterpret_cast<float4*>(fr + 4)  = make_float4(fk[4], fk[5], fk[6], fk[7]);
    *reinterpret_cast<float4*>(fr + 8)  = make_float4(fk[8], fk[9], fk[10], fk[11]);
    *reinterpret_cast<float4*>(fr + 12) = make_float4(win[0][4], win[1][4], win[2][4], win[3][4]);
  };

  auto p2step = [&](int tt) {
    const float* row = &feat[tt * TSTRIDE + p2 * 16];
    const float4 a4 = *reinterpret_cast<const float4*>(row + i0);
    const float4 b4 = *reinterpret_cast<const float4*>(row + j0);
    float fa[4] = {a4.x, a4.y, a4.z, a4.w};
    float fb[4] = {b4.x, b4.y, b4.z, b4.w};
    float sa[4], db[4];
    #pragma unroll
    for (int i = 0; i < 4; i++) { sa[i] = fa[i] + pa[i]; db[i] = fb[i] - pb[i]; }
    #pragma unroll
    for (int i = 0; i < 4; i++)
      #pragma unroll
      for (int j = 0; j < 4; j++) accv[i][j] += sa[i] * db[j];
    #pragma unroll
    for (int i = 0; i < 4; i++) { fsum[i] += fa[i]; pa[i] = fa[i]; pb[i] = fb[i]; }
  };

  // ===== chunk 0 (peeled) =====
  loadrg(0);
  writexs();
  __syncthreads();                 // syncB: xs ready
  conv();
  loadrg(1);                       // prefetch chunk 1 (latency hides under p2)
  __syncthreads();                 // syncC: feat ready
  {
    const float* r0 = &feat[p2 * 16];
    const float4 a4 = *reinterpret_cast<const float4*>(r0 + i0);
    const float4 b4 = *reinterpret_cast<const float4*>(r0 + j0);
    f0a[0] = a4.x; f0a[1] = a4.y; f0a[2] = a4.z; f0a[3] = a4.w;
    f0b[0] = b4.x; f0b[1] = b4.y; f0b[2] = b4.z; f0b[3] = b4.w;
    #pragma unroll
    for (int i = 0; i < 4; i++) { pa[i] = f0a[i]; pb[i] = f0b[i]; fsum[i] = f0a[i]; }
  }
  #pragma unroll
  for (int tt = 1; tt < CHUNK; tt++) p2step(tt);

  // ===== chunks 1..5 =====
  for (int chunk = 1; chunk < NCHUNK; chunk++) {
    writexs();                     // write prefetched regs (xs reuse safe: syncC)
    __syncthreads();               // syncB: xs ready + feat(prev p2) protected
    conv();
    if (chunk < NCHUNK - 1) loadrg(chunk + 1);
    __syncthreads();               // syncC: feat ready + xs-read complete
    #pragma unroll
    for (int tt = 0; tt < CHUNK; tt++) p2step(tt);
  }

  // ===== fused MLP-1 epilogue (byte-identical to R7/R14, verified) =====
  {
    const int ph = th4 + (p2 >> 2), pw = tw4 + (p2 & 3);
    const int pixbase = (ph * WW + pw) * SIG;      // w1 row base for this pixel
    float lv1b[4];
    #pragma unroll
    for (int j = 0; j < 4; j++) lv1b[j] = pb[j] - f0b[j];

    // special rows, balanced across jt (f0a/pa/fsum shared per-it):
    float spv[4]; int spr[4]; int nsp = 0;
    if (jt == 0) {                                 // lvl1, channels i0..i0+3
      nsp = 4;
      #pragma unroll
      for (int ii = 0; ii < 4; ii++) { spv[ii] = pa[ii] - f0a[ii]; spr[ii] = pixbase + i0 + ii; }
    } else if (jt == 1) {                          // lvl2[c][16] (A x t)
      nsp = 4;
      #pragma unroll
      for (int ii = 0; ii < 4; ii++) {
        spv[ii] = (fsum[ii] - 95.5f * f0a[ii] - 0.5f * pa[ii]) * (1.f / 95.f);
        spr[ii] = pixbase + NFC + (i0 + ii) * NFC + 16;
      }
    } else if (jt == 2) {                          // lvl2[16][c] (t x B)
      nsp = 4;
      #pragma unroll
      for (int ii = 0; ii < 4; ii++) {
        spv[ii] = (95.5f * pa[ii] + 0.5f * f0a[ii] - fsum[ii]) * (1.f / 95.f);
        spr[ii] = pixbase + NFC + 16 * NFC + (i0 + ii);
      }
    } else {                                       // jt == 3: const rows
      if (it == 0) { nsp = 1; spv[0] = 1.0f; spr[0] = pixbase + 16; }
      if (it == 1) { nsp = 1; spv[0] = 0.5f; spr[0] = pixbase + NFC + 16 * NFC + 16; }
    }

    float hs0 = 0.f, hs1 = 0.f;
    #pragma unroll
    for (int half = 0; half < 2; half++) {
      const int n0 = half * 16;
      float h[16];
      #pragma unroll
      for (int q = 0; q < 16; q++) h[q] = 0.f;

      #pragma unroll
      for (int ii = 0; ii < 4; ii++) {
        #pragma unroll
        for (int jj = 0; jj < 4; jj++) {
          const float val = 0.5f * accv[ii][jj] - f0a[ii] * lv1b[jj];
          const float* wr = w1 + (size_t)(pixbase + NFC + (i0 + ii) * NFC + (j0 + jj)) * 32 + n0;
          const float4 wa = *reinterpret_cast<const float4*>(wr);
          const float4 wb = *reinterpret_cast<const float4*>(wr + 4);
          const float4 wc = *reinterpret_cast<const float4*>(wr + 8);
          const float4 wd = *reinterpret_cast<const float4*>(wr + 12);
          h[0]  += val * wa.x; h[1]  += val * wa.y; h[2]  += val * wa.z; h[3]  += val * wa.w;
          h[4]  += val * wb.x; h[5]  += val * wb.y; h[6]  += val * wb.z; h[7]  += val * wb.w;
          h[8]  += val * wc.x; h[9]  += val * wc.y; h[10] += val * wc.z; h[11] += val * wc.w;
          h[12] += val * wd.x; h[13] += val * wd.y; h[14] += val * wd.z; h[15] += val * wd.w;
        }
      }
      #pragma unroll
      for (int sp = 0; sp < 4; sp++) {             // static unroll (rule #20)
        if (sp < nsp) {
          const float val = spv[sp];
          const float* wr = w1 + (size_t)spr[sp] * 32 + n0;
          const float4 wa = *reinterpret_cast<const float4*>(wr);
          const float4 wb = *reinterpret_cast<const float4*>(wr + 4);
          const float4 wc = *reinterpret_cast<const float4*>(wr + 8);
          const float4 wd = *reinterpret_cast<const float4*>(wr + 12);
          h[0]  += val * wa.x; h[1]  += val * wa.y; h[2]  += val * wa.z; h[3]  += val * wa.w;
          h[4]  += val * wb.x; h[5]  += val * wb.y; h[6]  += val * wb.z; h[7]  += val * wb.w;
          h[8]  += val * wc.x; h[9]  += val * wc.y; h[10] += val * wc.z; h[11] += val * wc.w;
          h[12] += val * wd.x; h[13] += val * wd.y; h[14] += val * wd.z; h[15] += val * wd.w;
        }
      }

      // ---- block-reduce h[16] over 256 threads (deterministic tree) ----
      __syncthreads();             // feat reads (p2 / prev half) complete
      #pragma unroll
      for (int q = 0; q < 16; q++) feat[tid * 17 + q] = h[q];   // stride-17: no conflicts
      __syncthreads();
      {
        const int r0 = tid >> 4, nn = tid & 15;
        float s = 0.f;
        #pragma unroll
        for (int j2 = 0; j2 < 16; j2++) s += feat[(r0 + 16 * j2) * 17 + nn];
        feat[256 * 17 + tid] = s;
      }
      __syncthreads();
      if (tid < 16) {
        float s = 0.f;
        #pragma unroll
        for (int r = 0; r < 16; r++) s += feat[256 * 17 + r * 16 + tid];
        if (half == 0) hs0 = s; else hs1 = s;
      }
    }

    if (tid < 16) {
      if (ATOMIC) {
        atomicAdd(&part[b * 32 + tid], hs0);
        atomicAdd(&part[b * 32 + 16 + tid], hs1);
      } else {
        part[tile * (BB * 32) + b * 32 + tid] = hs0;
        part[tile * (BB * 32) + b * 32 + 16 + tid] = hs1;
      }
    }
  }
}

// ---------------------------------------------------------------------------
// Kernel 2: partial-reduce + MLP layers 2-4. 64 blocks (one per b) x 256 thr.
// npart = 25 (tile partials), fixed order -> deterministic.
// ---------------------------------------------------------------------------
__global__ __launch_bounds__(256) void mlp_tail(
    const float* __restrict__ part, int npart, const float* __restrict__ b1,
    const float* __restrict__ w2, const float* __restrict__ b2,
    const float* __restrict__ w3, const float* __restrict__ b3,
    const float* __restrict__ w4, const float* __restrict__ b4,
    float* __restrict__ out)
{
  __shared__ float red[8][33];
  const int tid = threadIdx.x;
  const int n = tid & 31;
  const int s = tid >> 5;            // 0..7
  const int b = blockIdx.x;

  float sum = 0.f;
  for (int p = s; p < npart; p += 8)
    sum += part[(size_t)p * (BB * 32) + b * 32 + n];
  red[s][n] = sum;
  __syncthreads();

  if (tid < 32) {
    float acc = red[0][n];
    #pragma unroll
    for (int q = 1; q < 8; q++) acc += red[q][n];

    float h = fmaxf(acc + b1[n], 0.f);

    float v = b2[n];
    #pragma unroll
    for (int k = 0; k < 32; k++)
      v += __shfl(h, k, 64) * w2[k * 32 + n];
    h = fmaxf(v, 0.f);

    v = b3[n];
    #pragma unroll
    for (int k = 0; k < 32; k++)
      v += __shfl(h, k, 64) * w3[k * 32 + n];
    h = fmaxf(v, 0.f);

    float p = h * w4[n];
    #pragma unroll
    for (int o = 16; o >= 1; o >>= 1) p += __shfl_xor(p, o, 64);
    if (n == 0) out[b] = p + b4[0];
  }
}

extern "C" void kernel_launch(void* const* d_in, const int* in_sizes, int n_in,
                              void* d_out, int out_size, void* d_ws, size_t ws_size,
                              hipStream_t stream) {
  const float* x  = (const float*)d_in[0];
  const float* cw = (const float*)d_in[1];
  const float* w1 = (const float*)d_in[3];
  const float* b1 = (const float*)d_in[4];
  const float* w2 = (const float*)d_in[5];
  const float* b2 = (const float*)d_in[6];
  const float* w3 = (const float*)d_in[7];
  const float* b3 = (const float*)d_in[8];
  const float* w4 = (const float*)d_in[9];
  const float* b4 = (const float*)d_in[10];
  float* out = (float*)d_out;

  const size_t part_bytes = (size_t)NTILE * BB * 32 * sizeof(float);  // 204.8 KB

  if (ws_size >= part_bytes) {
    float* part = (float*)d_ws;
    sig_mlp1<false><<<dim3(1600), dim3(256), 0, stream>>>(x, cw, w1, part);
    mlp_tail<<<dim3(64), dim3(256), 0, stream>>>(part, NTILE, b1, w2, b2, w3, b3, w4, b4, out);
  } else {
    float* acc = (float*)d_ws;   // 8 KB
    hipMemsetAsync(acc, 0, BB * 32 * sizeof(float), stream);
    sig_mlp1<true><<<dim3(1600), dim3(256), 0, stream>>>(x, cw, w1, acc);
    mlp_tail<<<dim3(64), dim3(256), 0, stream>>>(acc, 1, b1, w2, b2, w3, b3, w4, b4, out);
  }
}

// Round 10
// 353.508 us; speedup vs baseline: 1.3601x; 1.1077x over previous
//
#include <hip/hip_runtime.h>

#define HH 20
#define WW 20
#define TT 96
#define BB 64
#define SIG 306
#define NFC 17
#define TSTRIDE 260    // feat per-t stride: 16pix*16ch + 4  (== 4 mod 32: conflict-free b128 writes)
#define CHUNK 16
#define NCHUNK 6
#define XT 199         // xs per-t stride
#define NTILE 25
#define FEATF 4176     // feat floats (4164 rounded to 16B)
#define SMEMF 7376     // max(feat+xs = 4176+3184, sigLDS+hpart = 4896+1056) + pad

typedef float float4u __attribute__((ext_vector_type(4), aligned(4)));

// ---------------------------------------------------------------------------
// Kernel 1 (R16): conv + signature + FUSED MLP-1 -> 25x64x32 partials.
// Main loop = frozen R2 structure. Block map = R9 dual-locality (verified:
// FETCH 174 MB — w1 deduped per-XCD, x replicated across XCDs).
// EPILOGUE REWRITTEN (the round's change): R7/R9's per-thread scatter walk
// (160 uncoalesced float4 w1 loads/thread, h[16] in regs -> VGPR 136,
// occ 10.5%, latency-bound at 553 GB/s) is replaced by:
//   phase A: threads write their sig values (same 306 formulas, verified)
//            to a 19.6 KB LDS arena overlaid on dead feat/xs.
//   phase B: thread (sg=tid>>3, n4=(tid&7)*4) streams h4 += sig[p][f] *
//            w1[(pixbase_p+f)*32+n4], f = sg step 32 -> wave-coalesced b128
//            w1 streams (1 KB/instr), each row read once/block, 1 small acc.
//   phase C: 32 partials per n reduced in fixed order (deterministic).
// ---------------------------------------------------------------------------
template<bool ATOMIC>
__global__ __launch_bounds__(256) void sig_mlp1(
    const float* __restrict__ x,    // (64,96,4,20,20)
    const float* __restrict__ cw,   // (12,4,3,3)
    const float* __restrict__ w1,   // (122400,32)
    float* __restrict__ part)       // (25,64,32) or (64,32) atomic
{
  __shared__ __align__(16) float smem[SMEMF];
  float* feat = smem;               // main loop: [15*260+..] / epi: sigLDS[16*306]
  float* xs   = smem + FEATF;       // main loop: [16*199]

  const int tid = threadIdx.x;
  const int blk = blockIdx.x;
  int tile, b;
  if (blk < 1536) {
    const int r = blk & 7, q = blk >> 3;       // q in [0,192)
    tile = r + 8 * (q >> 6);                   // r, r+8, r+16
    b = q & 63;
  } else {
    tile = 24;
    b = blk - 1536;
  }
  const int th4 = (tile / 5) * 4, tw4 = (tile % 5) * 4;
  const float* xb0 = x + (size_t)b * TT * 1600;

  // ---- staging precompute: 2304 = 9*256 halo values per chunk ----
  int g_off[9], l_off[9];
  #pragma unroll
  for (int r = 0; r < 9; r++) {
    int idx = r * 256 + tid;
    int t = idx / 144, q = idx % 144;
    int ci = q / 36, pos = q % 36, row = pos / 6, col = pos % 6;
    int gr = th4 - 1 + row, gc = tw4 - 1 + col;
    bool valid = (gr >= 0 && gr < HH && gc >= 0 && gc < WW);
    g_off[r] = valid ? (t * 1600 + ci * 400 + gr * WW + gc) : -1;
    l_off[r] = t * XT + ci * 48 + row * 8 + col;
  }

  const int cpix = tid >> 4, ctt = tid & 15;
  const int cpy = cpix >> 2, cpx = cpix & 3;

  const int p2 = tid >> 4;
  const int rr = tid & 15, it = rr >> 2, jt = rr & 3;
  const int i0 = it * 4, j0 = jt * 4;

  float accv[4][4];
  float f0a[4], f0b[4], pa[4], pb[4], fsum[4];
  float rg[9];                       // prefetch registers (live across p2)
  #pragma unroll
  for (int i = 0; i < 4; i++) {
    #pragma unroll
    for (int j = 0; j < 4; j++) accv[i][j] = 0.f;
  }

  auto loadrg = [&](int chunk) {
    const float* xbc = xb0 + (size_t)chunk * CHUNK * 1600;
    #pragma unroll
    for (int r = 0; r < 9; r++)
      rg[r] = (g_off[r] >= 0) ? xbc[g_off[r]] : 0.f;
  };
  auto writexs = [&]() {
    #pragma unroll
    for (int r = 0; r < 9; r++) xs[l_off[r]] = rg[r];
  };

  auto conv = [&]() {
    float win[4][9];
    const int wb2 = ctt * XT;
    #pragma unroll
    for (int ci = 0; ci < 4; ci++)
      #pragma unroll
      for (int dy = 0; dy < 3; dy++)
        #pragma unroll
        for (int dxx = 0; dxx < 3; dxx++)
          win[ci][dy * 3 + dxx] = xs[wb2 + ci * 48 + (cpy + dy) * 8 + (cpx + dxx)];

    float fk[12];
    #pragma unroll
    for (int k = 0; k < 12; k++) {
      float a = 0.f;
      #pragma unroll
      for (int ci = 0; ci < 4; ci++) {
        #pragma unroll
        for (int p = 0; p < 9; p++)
          a += win[ci][p] * cw[k * 36 + ci * 9 + p];   // uniform -> scalar load
      }
      fk[k] = a;
    }
    float* fr = &feat[ctt * TSTRIDE + cpix * 16];
    *reinterpret_cast<float4*>(fr + 0)  = make_float4(fk[0], fk[1], fk[2], fk[3]);
    *reinterpret_cast<float4*>(fr + 4)  = make_float4(fk[4], fk[5], fk[6], fk[7]);
    *reinterpret_cast<float4*>(fr + 8)  = make_float4(fk[8], fk[9], fk[10], fk[11]);
    *reinterpret_cast<float4*>(fr + 12) = make_float4(win[0][4], win[1][4], win[2][4], win[3][4]);
  };

  auto p2step = [&](int tt) {
    const float* row = &feat[tt * TSTRIDE + p2 * 16];
    const float4 a4 = *reinterpret_cast<const float4*>(row + i0);
    const float4 b4 = *reinterpret_cast<const float4*>(row + j0);
    float fa[4] = {a4.x, a4.y, a4.z, a4.w};
    float fb[4] = {b4.x, b4.y, b4.z, b4.w};
    float sa[4], db[4];
    #pragma unroll
    for (int i = 0; i < 4; i++) { sa[i] = fa[i] + pa[i]; db[i] = fb[i] - pb[i]; }
    #pragma unroll
    for (int i = 0; i < 4; i++)
      #pragma unroll
      for (int j = 0; j < 4; j++) accv[i][j] += sa[i] * db[j];
    #pragma unroll
    for (int i = 0; i < 4; i++) { fsum[i] += fa[i]; pa[i] = fa[i]; pb[i] = fb[i]; }
  };

  // ===== chunk 0 (peeled) =====
  loadrg(0);
  writexs();
  __syncthreads();                 // syncB: xs ready
  conv();
  loadrg(1);                       // prefetch chunk 1 (latency hides under p2)
  __syncthreads();                 // syncC: feat ready
  {
    const float* r0 = &feat[p2 * 16];
    const float4 a4 = *reinterpret_cast<const float4*>(r0 + i0);
    const float4 b4 = *reinterpret_cast<const float4*>(r0 + j0);
    f0a[0] = a4.x; f0a[1] = a4.y; f0a[2] = a4.z; f0a[3] = a4.w;
    f0b[0] = b4.x; f0b[1] = b4.y; f0b[2] = b4.z; f0b[3] = b4.w;
    #pragma unroll
    for (int i = 0; i < 4; i++) { pa[i] = f0a[i]; pb[i] = f0b[i]; fsum[i] = f0a[i]; }
  }
  #pragma unroll
  for (int tt = 1; tt < CHUNK; tt++) p2step(tt);

  // ===== chunks 1..5 =====
  for (int chunk = 1; chunk < NCHUNK; chunk++) {
    writexs();                     // write prefetched regs (xs reuse safe: syncC)
    __syncthreads();               // syncB: xs ready + feat(prev p2) protected
    conv();
    if (chunk < NCHUNK - 1) loadrg(chunk + 1);
    __syncthreads();               // syncC: feat ready + xs-read complete
    #pragma unroll
    for (int tt = 0; tt < CHUNK; tt++) p2step(tt);
  }

  // ===== fused MLP-1 epilogue v2 =====
  {
    float lv1b[4];
    #pragma unroll
    for (int j = 0; j < 4; j++) lv1b[j] = pb[j] - f0b[j];

    __syncthreads();               // all feat/xs reads done; smem now sigLDS

    // ---- phase A: write this thread's sig values (same formulas, verified) ----
    float* sp2 = &smem[p2 * SIG];
    #pragma unroll
    for (int ii = 0; ii < 4; ii++) {
      #pragma unroll
      for (int jj = 0; jj < 4; jj++)
        sp2[NFC + (i0 + ii) * NFC + (j0 + jj)] =
            0.5f * accv[ii][jj] - f0a[ii] * lv1b[jj];
    }
    if (jt == 0) {                                 // lvl1, channels i0..i0+3
      #pragma unroll
      for (int ii = 0; ii < 4; ii++) sp2[i0 + ii] = pa[ii] - f0a[ii];
    } else if (jt == 1) {                          // lvl2[c][16] (A x t)
      #pragma unroll
      for (int ii = 0; ii < 4; ii++)
        sp2[NFC + (i0 + ii) * NFC + 16] =
            (fsum[ii] - 95.5f * f0a[ii] - 0.5f * pa[ii]) * (1.f / 95.f);
    } else if (jt == 2) {                          // lvl2[16][c] (t x B)
      #pragma unroll
      for (int ii = 0; ii < 4; ii++)
        sp2[NFC + 16 * NFC + (i0 + ii)] =
            (95.5f * pa[ii] + 0.5f * f0a[ii] - fsum[ii]) * (1.f / 95.f);
    } else {                                       // jt == 3: const rows
      if (it == 0) sp2[16] = 1.0f;
      if (it == 1) sp2[NFC + 16 * NFC + 16] = 0.5f;
    }
    __syncthreads();               // sigLDS complete

    // ---- phase B: coalesced block-GEMM. thread = (sg, n4); w1 rows stream ----
    const int n4 = (tid & 7) * 4;
    const int sg = tid >> 3;       // 0..31
    float h4[4] = {0.f, 0.f, 0.f, 0.f};
    #pragma unroll
    for (int p = 0; p < 16; p++) {
      const int phh = th4 + (p >> 2), pww = tw4 + (p & 3);
      const float* wp = w1 + (size_t)((phh * WW + pww) * SIG) * 32 + n4;
      const float* sv = &smem[p * SIG];
      for (int f = sg; f < SIG; f += 32) {
        const float v = sv[f];                              // LDS, conflict-free
        const float4 w4v = *reinterpret_cast<const float4*>(&wp[(size_t)f * 32]);
        h4[0] += v * w4v.x; h4[1] += v * w4v.y;
        h4[2] += v * w4v.z; h4[3] += v * w4v.w;
      }
    }

    // ---- phase C: reduce 32 sg-partials per n (fixed order, deterministic) ----
    float* hp = &smem[16 * SIG];   // [32][33]
    __syncthreads();               // phase-B sigLDS reads done before overwrite? (hp is past sigLDS region — no overlap, barrier still orders writes)
    #pragma unroll
    for (int j = 0; j < 4; j++) hp[sg * 33 + n4 + j] = h4[j];
    __syncthreads();
    if (tid < 32) {
      float a = 0.f;
      #pragma unroll
      for (int s2 = 0; s2 < 32; s2++) a += hp[s2 * 33 + tid];
      if (ATOMIC) {
        atomicAdd(&part[b * 32 + tid], a);
      } else {
        part[tile * (BB * 32) + b * 32 + tid] = a;
      }
    }
  }
}

// ---------------------------------------------------------------------------
// Kernel 2: partial-reduce + MLP layers 2-4. 64 blocks (one per b) x 256 thr.
// npart = 25 (tile partials), fixed order -> deterministic.
// ---------------------------------------------------------------------------
__global__ __launch_bounds__(256) void mlp_tail(
    const float* __restrict__ part, int npart, const float* __restrict__ b1,
    const float* __restrict__ w2, const float* __restrict__ b2,
    const float* __restrict__ w3, const float* __restrict__ b3,
    const float* __restrict__ w4, const float* __restrict__ b4,
    float* __restrict__ out)
{
  __shared__ float red[8][33];
  const int tid = threadIdx.x;
  const int n = tid & 31;
  const int s = tid >> 5;            // 0..7
  const int b = blockIdx.x;

  float sum = 0.f;
  for (int p = s; p < npart; p += 8)
    sum += part[(size_t)p * (BB * 32) + b * 32 + n];
  red[s][n] = sum;
  __syncthreads();

  if (tid < 32) {
    float acc = red[0][n];
    #pragma unroll
    for (int q = 1; q < 8; q++) acc += red[q][n];

    float h = fmaxf(acc + b1[n], 0.f);

    float v = b2[n];
    #pragma unroll
    for (int k = 0; k < 32; k++)
      v += __shfl(h, k, 64) * w2[k * 32 + n];
    h = fmaxf(v, 0.f);

    v = b3[n];
    #pragma unroll
    for (int k = 0; k < 32; k++)
      v += __shfl(h, k, 64) * w3[k * 32 + n];
    h = fmaxf(v, 0.f);

    float p = h * w4[n];
    #pragma unroll
    for (int o = 16; o >= 1; o >>= 1) p += __shfl_xor(p, o, 64);
    if (n == 0) out[b] = p + b4[0];
  }
}

extern "C" void kernel_launch(void* const* d_in, const int* in_sizes, int n_in,
                              void* d_out, int out_size, void* d_ws, size_t ws_size,
                              hipStream_t stream) {
  const float* x  = (const float*)d_in[0];
  const float* cw = (const float*)d_in[1];
  const float* w1 = (const float*)d_in[3];
  const float* b1 = (const float*)d_in[4];
  const float* w2 = (const float*)d_in[5];
  const float* b2 = (const float*)d_in[6];
  const float* w3 = (const float*)d_in[7];
  const float* b3 = (const float*)d_in[8];
  const float* w4 = (const float*)d_in[9];
  const float* b4 = (const float*)d_in[10];
  float* out = (float*)d_out;

  const size_t part_bytes = (size_t)NTILE * BB * 32 * sizeof(float);  // 204.8 KB

  if (ws_size >= part_bytes) {
    float* part = (float*)d_ws;
    sig_mlp1<false><<<dim3(1600), dim3(256), 0, stream>>>(x, cw, w1, part);
    mlp_tail<<<dim3(64), dim3(256), 0, stream>>>(part, NTILE, b1, w2, b2, w3, b3, w4, b4, out);
  } else {
    float* acc = (float*)d_ws;   // 8 KB
    hipMemsetAsync(acc, 0, BB * 32 * sizeof(float), stream);
    sig_mlp1<true><<<dim3(1600), dim3(256), 0, stream>>>(x, cw, w1, acc);
    mlp_tail<<<dim3(64), dim3(256), 0, stream>>>(acc, 1, b1, w2, b2, w3, b3, w4, b4, out);
  }
}